// Round 5
// baseline (480.361 us; speedup 1.0000x reference)
//
#include <hip/hip_runtime.h>
#include <cstdint>

#define BATCH 16
#define CH 1024
#define CIN 256
#define NSP 2048   // H*W = 64*32
#define BN_EPS 1e-5f

typedef _Float16 f16;
typedef f16   f16x4 __attribute__((ext_vector_type(4)));
typedef f16   f16x8 __attribute__((ext_vector_type(8)));
typedef float f32x4 __attribute__((ext_vector_type(4)));
typedef float f32x16 __attribute__((ext_vector_type(16)));

typedef __attribute__((address_space(3))) void lds_t;
typedef __attribute__((address_space(1))) const void gbl_t;

// async 16B/lane global->LDS (LDS dest = wave-uniform base + lane*16)
__device__ __forceinline__ void gld16(void* l, const void* g) {
    __builtin_amdgcn_global_load_lds((gbl_t*)g, (lds_t*)l, 16, 0, 0);
}

// ---------------------------------------------------------------------------
// P0: weights -> fp16; fold BN+bias into inv/off
// ---------------------------------------------------------------------------
__global__ __launch_bounds__(256) void k_prep(
    const float* __restrict__ tw, const float* __restrict__ pw,
    const float* __restrict__ gw, const float* __restrict__ ww,
    const float* __restrict__ wb, const float* __restrict__ gamma,
    const float* __restrict__ beta, const float* __restrict__ mean,
    const float* __restrict__ var,
    f16* __restrict__ w_all, float* __restrict__ inv_out, float* __restrict__ off_out)
{
    int id = blockIdx.x * 256 + threadIdx.x;
    if (id < 4 * 262144) {
        int sel = id >> 18, off = id & 262143;
        const float* src = sel == 0 ? tw : sel == 1 ? pw : sel == 2 ? gw : ww;
        w_all[id] = (f16)src[off];
    } else {
        int c = id - 4 * 262144;
        if (c < CH) {
            float iv = gamma[c] * rsqrtf(var[c] + BN_EPS);
            inv_out[c] = iv;
            off_out[c] = (wb[c] - mean[c]) * iv + beta[c];
        }
    }
}

// ---------------------------------------------------------------------------
// P1: x [B,C,N] fp32 -> xT [B,N,C] fp16
// ---------------------------------------------------------------------------
__global__ __launch_bounds__(256) void k_transpose_x(
    const float* __restrict__ x, f16* __restrict__ xT)
{
    __shared__ float tile[64 * 65];
    int t = threadIdx.x;
    int n0 = blockIdx.x * 64, c0 = blockIdx.y * 64, b = blockIdx.z;
    const float* xb = x + (size_t)b * CH * NSP;
    for (int k = 0; k < 4; ++k) {
        int id = t + 256 * k;
        int row = id >> 4, cc = id & 15;
        float4 v = *(const float4*)(xb + (size_t)(c0 + row) * NSP + n0 + cc * 4);
        tile[row * 65 + cc * 4 + 0] = v.x;
        tile[row * 65 + cc * 4 + 1] = v.y;
        tile[row * 65 + cc * 4 + 2] = v.z;
        tile[row * 65 + cc * 4 + 3] = v.w;
    }
    __syncthreads();
    f16* xTb = xT + (size_t)b * NSP * CH;
    for (int k = 0; k < 2; ++k) {
        int id = t + 256 * k;
        int n = id >> 3, c8 = id & 7;
        f16x8 o;
        #pragma unroll
        for (int j = 0; j < 8; ++j) o[j] = (f16)tile[(c8 * 8 + j) * 65 + n];
        *(f16x8*)(xTb + (size_t)(n0 + n) * CH + c0 + c8 * 8) = o;
    }
}

// ---------------------------------------------------------------------------
// K1: QKV projections, m97-style: BK=64, global_load_lds(16B) staging into
// XOR-swizzled unpadded LDS tiles. grid (N/64, B, 3); tile 64n x 256o.
// ---------------------------------------------------------------------------
__global__ __launch_bounds__(256, 3) void k_qkv(
    const f16* __restrict__ xT, const f16* __restrict__ w_all,
    const float* __restrict__ tb, const float* __restrict__ pb,
    const float* __restrict__ gb,
    f16* __restrict__ theta, f16* __restrict__ phiT, f16* __restrict__ gT)
{
    __shared__ char smem[40960];
    f16* a_lds = (f16*)smem;            // [64][64]  swizzled (8 KB)
    f16* b_lds = (f16*)(smem + 8192);   // [256][64] swizzled (32 KB)
    int t = threadIdx.x;
    int w = t >> 6, lane = t & 63, l15 = lane & 15, q = lane >> 4;
    int sw = l15 & 7;
    int n0 = blockIdx.x * 64, b = blockIdx.y, set = blockIdx.z;
    const f16* W  = w_all + (size_t)set * (CIN * CH);
    const f16* xA = xT + ((size_t)b * NSP + n0) * CH;

    int rA  = lane >> 3;             // row-in-window 0..7
    int ccs = (lane & 7) ^ rA;       // swizzled global chunk for this lane

    f32x4 acc[4][4];
    #pragma unroll
    for (int i = 0; i < 4; ++i)
        #pragma unroll
        for (int j = 0; j < 4; ++j) acc[i][j] = (f32x4){0.f, 0.f, 0.f, 0.f};

    for (int it = 0; it < 16; ++it) {
        #pragma unroll
        for (int i = 0; i < 2; ++i) {
            int win = w * 2 + i;
            int n = win * 8 + rA;
            gld16((char*)a_lds + win * 1024,
                  xA + (size_t)n * CH + it * 64 + ccs * 8);
        }
        #pragma unroll
        for (int i = 0; i < 8; ++i) {
            int win = w * 8 + i;
            int o = win * 8 + rA;
            gld16((char*)b_lds + win * 1024,
                  W + (size_t)o * CH + it * 64 + ccs * 8);
        }
        __syncthreads();

        #pragma unroll
        for (int kl = 0; kl < 2; ++kl) {
            int c16 = kl * 4 + q;
            int pos = (c16 ^ sw) & 7;
            f16x8 af[4], bfr[4];
            #pragma unroll
            for (int tn = 0; tn < 4; ++tn)
                af[tn] = *(const f16x8*)(a_lds + (16 * tn + l15) * 64 + pos * 8);
            #pragma unroll
            for (int to = 0; to < 4; ++to)
                bfr[to] = *(const f16x8*)(b_lds + (64 * w + 16 * to + l15) * 64 + pos * 8);
            #pragma unroll
            for (int tn = 0; tn < 4; ++tn)
                #pragma unroll
                for (int to = 0; to < 4; ++to)
                    acc[tn][to] = __builtin_amdgcn_mfma_f32_16x16x32_f16(
                        af[tn], bfr[to], acc[tn][to], 0, 0, 0);
        }
        __syncthreads();
    }

    const float* bias = set == 0 ? tb : set == 1 ? pb : gb;
    float bv[4];
    #pragma unroll
    for (int to = 0; to < 4; ++to) bv[to] = bias[64 * w + 16 * to + l15];

    if (set < 2) {
        f16* e_lds = (f16*)smem;  // [64][256]
        #pragma unroll
        for (int tn = 0; tn < 4; ++tn)
            #pragma unroll
            for (int to = 0; to < 4; ++to)
                #pragma unroll
                for (int r = 0; r < 4; ++r)
                    e_lds[(16 * tn + 4 * q + r) * 256 + 64 * w + 16 * to + l15] =
                        (f16)(acc[tn][to][r] + bv[to]);
        __syncthreads();
        f16* dst = (set == 0 ? theta : phiT) + ((size_t)b * NSP + n0) * CIN;
        for (int k2 = 0; k2 < 8; ++k2) {
            int id = t + 256 * k2;
            *(f16x8*)(dst + id * 8) = *(const f16x8*)(e_lds + id * 8);
        }
    } else {
        f16* e_lds = (f16*)smem;  // [256][72]
        #pragma unroll
        for (int tn = 0; tn < 4; ++tn)
            #pragma unroll
            for (int to = 0; to < 4; ++to)
                #pragma unroll
                for (int r = 0; r < 4; ++r)
                    e_lds[(64 * w + 16 * to + l15) * 72 + 16 * tn + 4 * q + r] =
                        (f16)(acc[tn][to][r] + bv[to]);
        __syncthreads();
        f16* dst = gT + (size_t)b * CIN * NSP + n0;
        for (int k2 = 0; k2 < 8; ++k2) {
            int id = t + 256 * k2;
            int o = id >> 3, cc = id & 7;
            *(f16x8*)(dst + (size_t)o * NSP + cc * 8) = *(const f16x8*)(e_lds + o * 72 + cc * 8);
        }
    }
}

// ---------------------------------------------------------------------------
// K2: flash attention v5 -- 32x32x16 MFMA (2x FLOP per LDS byte).
// KVBLK=64, 4 waves: wave w = (kh=w>>1, qh=w&1) computes S^T subtile
// [32k (kh)][32q (qh)]; PV splits cin across waves (wave owns 64 cin for all
// 64 q). Online softmax merges kh halves via pmax/psum LDS each iter; per-q
// alpha bounced via alpha_lds for yacc rescale. Staging = pure gld16 DMA,
// single-buffered: phi issued post-(b) (covered by PV), g post-(c) (covered
// by S). grid (B, N/64) for XCD pinning. LDS 76.5KB -> 2 blocks/CU.
// ---------------------------------------------------------------------------
__global__ __launch_bounds__(256, 2) void k_attn(
    const f16* __restrict__ theta, const f16* __restrict__ phiT,
    const f16* __restrict__ gT, f16* __restrict__ y)
{
    __shared__ char smem[76544];
    f16* phi_lds = (f16*)smem;                 // [64][256] swizzled (32 KB)
    f16* g_lds   = (f16*)(smem + 32768);       // [256][64] swizzled (32 KB)
    f16* p_lds   = (f16*)(smem + 65536);       // [64][76]  (9728 B)
    float* pmax_lds  = (float*)(smem + 75264); // [2][64]
    float* psum_lds  = (float*)(smem + 75776); // [2][64]
    float* alpha_lds = (float*)(smem + 76288); // [64]

    int t = threadIdx.x;
    int w = t >> 6, lane = t & 63;
    int l31 = lane & 31, hi = lane >> 5;
    int qh = w & 1, kh = w >> 1;
    int b = blockIdx.x, n0 = blockIdx.y * 64;

    const f16* thb  = theta + (size_t)b * NSP * CIN;
    const f16* phib = phiT + (size_t)b * NSP * CIN;
    const f16* gTb  = gT + (size_t)b * CIN * NSP;

    // theta regs (B-operand): col q = n0+32qh+l31, k = 16*step + 8*hi + j
    f16x8 th[16];
    {
        const f16* tp = thb + (size_t)(n0 + qh * 32 + l31) * CIN + 8 * hi;
        #pragma unroll
        for (int s = 0; s < 16; ++s) th[s] = *(const f16x8*)(tp + s * 16);
    }

    f32x16 acc[2][2];   // [Mt: q-half][Nt: cin sub-tile of this wave's quarter]
    #pragma unroll
    for (int i = 0; i < 2; ++i)
        #pragma unroll
        for (int j = 0; j < 2; ++j)
            #pragma unroll
            for (int r = 0; r < 16; ++r) acc[i][j][r] = 0.f;
    float m_run = -INFINITY, l_run = 0.f;

    // phi DMA: 32 windows of 1KB = 2 rows x 512B. lane -> (row_in=hi, chunk)
    int p_cdst = lane & 31;
    // g DMA: 32 windows of 1KB = 8 rows x 128B. lane -> (row_in, chunk)
    int g_rin = lane >> 3, g_cdst = lane & 7;

    #define DMA_PHI(IT)                                                         \
        _Pragma("unroll")                                                       \
        for (int i_ = 0; i_ < 8; ++i_) {                                        \
            int win_ = w * 8 + i_;                                              \
            int row_ = win_ * 2 + hi;                                           \
            int cs_ = (p_cdst & 24) | ((p_cdst ^ row_) & 7);                    \
            gld16((char*)phi_lds + win_ * 1024,                                 \
                  phib + (size_t)((IT) * 64 + row_) * CIN + cs_ * 8);           \
        }
    #define DMA_G(IT)                                                           \
        _Pragma("unroll")                                                       \
        for (int i_ = 0; i_ < 8; ++i_) {                                        \
            int win_ = w * 8 + i_;                                              \
            int row_ = win_ * 8 + g_rin;                                        \
            int cs_ = g_cdst ^ (row_ & 7);                                      \
            gld16((char*)g_lds + win_ * 1024,                                   \
                  gTb + (size_t)row_ * NSP + (IT) * 64 + cs_ * 8);              \
        }

    DMA_PHI(0)
    DMA_G(0)
    __syncthreads();

    int srow = kh * 32 + l31;        // phi row for S A-operand
    int qrow = qh * 32 + l31;        // this thread's softmax q-column
    int mli  = kh * 64 + qrow;       // partial-max/sum slot

    for (int it = 0; it < 32; ++it) {
        // ---- S^T subtile: D[m=k(32,kh)][n=q(32,qh)], K=256 in 16 steps
        f32x16 sacc;
        #pragma unroll
        for (int r = 0; r < 16; ++r) sacc[r] = 0.f;
        #pragma unroll
        for (int s = 0; s < 16; ++s) {
            int ch = 2 * s + hi;
            int slot = (ch & 24) | ((ch ^ srow) & 7);
            f16x8 af = *(const f16x8*)(phi_lds + srow * 256 + slot * 8);
            sacc = __builtin_amdgcn_mfma_f32_32x32x16_f16(af, th[s], sacc, 0, 0, 0);
        }

        // ---- partial max over this wave's 32 k-rows for col qrow
        float tmax = sacc[0];
        #pragma unroll
        for (int r = 1; r < 16; ++r) tmax = fmaxf(tmax, sacc[r]);
        tmax = fmaxf(tmax, __shfl_xor(tmax, 32));
        if (lane < 32) pmax_lds[mli] = tmax;
        __syncthreads();                                   // (a)

        float tile_max = fmaxf(tmax, pmax_lds[mli ^ 64]);
        float mnew  = fmaxf(m_run, tile_max);
        float alpha = __expf(m_run - mnew);
        m_run = mnew;
        float rs = 0.f;
        float pv[16];
        #pragma unroll
        for (int r = 0; r < 16; ++r) {
            pv[r] = __expf(sacc[r] - mnew);
            rs += pv[r];
        }
        rs += __shfl_xor(rs, 32);
        if (lane < 32) {
            psum_lds[mli] = rs;
            if (kh == 0) alpha_lds[qrow] = alpha;
        }
        // P -> p_lds [q][76]: rows m=(reg&3)+8*(reg>>2)+4hi -> k=kh*32+8g+4hi+rr
        #pragma unroll
        for (int g4 = 0; g4 < 4; ++g4) {
            f16x4 pk = { (f16)pv[4*g4+0], (f16)pv[4*g4+1], (f16)pv[4*g4+2], (f16)pv[4*g4+3] };
            *(f16x4*)(p_lds + qrow * 76 + kh * 32 + 8 * g4 + 4 * hi) = pk;
        }
        __syncthreads();                                   // (b)

        if (it < 31) DMA_PHI(it + 1)                       // covered by PV

        l_run = l_run * alpha + rs + psum_lds[mli ^ 64];

        // ---- rescale yacc (rows are reg-indexed q; alpha via LDS broadcast)
        f32x4 av[2][4];
        float mn = 1.0f;
        #pragma unroll
        for (int Mt = 0; Mt < 2; ++Mt)
            #pragma unroll
            for (int g4 = 0; g4 < 4; ++g4) {
                av[Mt][g4] = *(const f32x4*)(alpha_lds + Mt * 32 + 8 * g4 + 4 * hi);
                mn = fminf(mn, fminf(fminf(av[Mt][g4][0], av[Mt][g4][1]),
                                     fminf(av[Mt][g4][2], av[Mt][g4][3])));
            }
        if (__any(mn < 1.0f)) {
            #pragma unroll
            for (int Mt = 0; Mt < 2; ++Mt)
                #pragma unroll
                for (int g4 = 0; g4 < 4; ++g4)
                    #pragma unroll
                    for (int rr = 0; rr < 4; ++rr) {
                        acc[Mt][0][4*g4+rr] *= av[Mt][g4][rr];
                        acc[Mt][1][4*g4+rr] *= av[Mt][g4][rr];
                    }
        }

        // ---- PV: D[m=q][n=cin(wave quarter)], K=64 in 4 steps
        #pragma unroll
        for (int ks = 0; ks < 4; ++ks) {
            f16x8 pa0 = *(const f16x8*)(p_lds + l31 * 76 + ks * 16 + 8 * hi);
            f16x8 pa1 = *(const f16x8*)(p_lds + (32 + l31) * 76 + ks * 16 + 8 * hi);
            int slot = (2 * ks + hi) ^ (l31 & 7);
            f16x8 gb0 = *(const f16x8*)(g_lds + (64 * w + l31) * 64 + slot * 8);
            f16x8 gb1 = *(const f16x8*)(g_lds + (64 * w + 32 + l31) * 64 + slot * 8);
            acc[0][0] = __builtin_amdgcn_mfma_f32_32x32x16_f16(pa0, gb0, acc[0][0], 0, 0, 0);
            acc[0][1] = __builtin_amdgcn_mfma_f32_32x32x16_f16(pa0, gb1, acc[0][1], 0, 0, 0);
            acc[1][0] = __builtin_amdgcn_mfma_f32_32x32x16_f16(pa1, gb0, acc[1][0], 0, 0, 0);
            acc[1][1] = __builtin_amdgcn_mfma_f32_32x32x16_f16(pa1, gb1, acc[1][1], 0, 0, 0);
        }
        __syncthreads();                                   // (c)

        if (it < 31) DMA_G(it + 1)                         // covered by next S
    }

    // ---- epilogue: y = acc / l, via LDS bounce for coalesced stores
    if (lane < 32 && kh == 0) alpha_lds[qrow] = 1.0f / l_run;
    __syncthreads();
    f16* e_lds = (f16*)smem;   // [64][264]
    #pragma unroll
    for (int Mt = 0; Mt < 2; ++Mt)
        #pragma unroll
        for (int g4 = 0; g4 < 4; ++g4) {
            f32x4 lv = *(const f32x4*)(alpha_lds + Mt * 32 + 8 * g4 + 4 * hi);
            #pragma unroll
            for (int rr = 0; rr < 4; ++rr) {
                int q = Mt * 32 + 8 * g4 + 4 * hi + rr;
                #pragma unroll
                for (int Nt = 0; Nt < 2; ++Nt) {
                    int cin = 64 * w + Nt * 32 + l31;
                    e_lds[q * 264 + cin] = (f16)(acc[Mt][Nt][4*g4+rr] * lv[rr]);
                }
            }
        }
    __syncthreads();
    f16* dst = y + ((size_t)b * NSP + n0) * CIN;
    for (int k2 = 0; k2 < 8; ++k2) {
        int id = t + 256 * k2;
        int row = id >> 5, cc = id & 31;
        *(f16x8*)(dst + (size_t)row * CIN + cc * 8) = *(const f16x8*)(e_lds + row * 264 + cc * 8);
    }
    #undef DMA_PHI
    #undef DMA_G
}

// ---------------------------------------------------------------------------
// K3: Z = w_w . y^T + BN + residual, k_qkv m97 structure.
// Tile 64n x 256c, K=CIN=256 in 4 BK=64 steps, gld16 -> swizzled LDS for
// BOTH operands. grid (N/64, C/256, B) = (32,4,16).
// ---------------------------------------------------------------------------
__global__ __launch_bounds__(256, 3) void k_out(
    const f16* __restrict__ yv, const f16* __restrict__ ww,
    const float* __restrict__ inv, const float* __restrict__ off,
    const float* __restrict__ x, float* __restrict__ out)
{
    __shared__ char smem[40960];
    f16*   a_lds = (f16*)smem;            // [64][64]  y tile, swizzled (8 KB)
    f16*   b_lds = (f16*)(smem + 8192);   // [256][64] w tile, swizzled (32 KB)
    float* z_lds = (float*)smem;          // [64][68] f32 bounce (17.4 KB, alias)
    int t = threadIdx.x;
    int w = t >> 6, lane = t & 63, l15 = lane & 15, q = lane >> 4;
    int sw = l15 & 7;
    int n0 = blockIdx.x * 64, cb = blockIdx.y * 256, b = blockIdx.z;

    const f16* yA = yv + ((size_t)b * NSP + n0) * CIN;
    const f16* W  = ww + (size_t)cb * CIN;

    int rA  = lane >> 3;             // row-in-window 0..7
    int ccs = (lane & 7) ^ rA;       // swizzled global chunk for this lane

    f32x4 acc[4][4];
    #pragma unroll
    for (int i = 0; i < 4; ++i)
        #pragma unroll
        for (int j = 0; j < 4; ++j) acc[i][j] = (f32x4){0.f, 0.f, 0.f, 0.f};

    for (int it = 0; it < 4; ++it) {
        #pragma unroll
        for (int i = 0; i < 2; ++i) {
            int win = w * 2 + i;
            int n = win * 8 + rA;
            gld16((char*)a_lds + win * 1024,
                  yA + (size_t)n * CIN + it * 64 + ccs * 8);
        }
        #pragma unroll
        for (int i = 0; i < 8; ++i) {
            int win = w * 8 + i;
            int o = win * 8 + rA;
            gld16((char*)b_lds + win * 1024,
                  W + (size_t)o * CIN + it * 64 + ccs * 8);
        }
        __syncthreads();

        #pragma unroll
        for (int kl = 0; kl < 2; ++kl) {
            int c16 = kl * 4 + q;
            int pos = (c16 ^ sw) & 7;
            f16x8 af[4], bfr[4];
            #pragma unroll
            for (int tn = 0; tn < 4; ++tn)
                af[tn] = *(const f16x8*)(a_lds + (16 * tn + l15) * 64 + pos * 8);
            #pragma unroll
            for (int to = 0; to < 4; ++to)
                bfr[to] = *(const f16x8*)(b_lds + (64 * w + 16 * to + l15) * 64 + pos * 8);
            #pragma unroll
            for (int tn = 0; tn < 4; ++tn)
                #pragma unroll
                for (int to = 0; to < 4; ++to)
                    acc[tn][to] = __builtin_amdgcn_mfma_f32_16x16x32_f16(
                        af[tn], bfr[to], acc[tn][to], 0, 0, 0);
        }
        __syncthreads();
    }

    // ---- epilogue: 4 slabs over `to` (c-fragment); z bounce for coalescing.
    float4 xv[4];
    #pragma unroll
    for (int k2 = 0; k2 < 4; ++k2) {
        int f = t + 256 * k2;
        int zrr = f >> 4, nn4 = f & 15;
        int c = cb + 64 * (zrr >> 4) + (zrr & 15);   // to = 0
        xv[k2] = *(const float4*)(x + ((size_t)b * CH + c) * NSP + n0 + nn4 * 4);
    }

    #pragma unroll
    for (int to = 0; to < 4; ++to) {
        #pragma unroll
        for (int tn = 0; tn < 4; ++tn)
            #pragma unroll
            for (int r = 0; r < 4; ++r)
                z_lds[(16 * w + l15) * 68 + 16 * tn + 4 * q + r] = acc[tn][to][r];
        __syncthreads();

        float4 nxt[4];
        if (to < 3) {
            #pragma unroll
            for (int k2 = 0; k2 < 4; ++k2) {
                int f = t + 256 * k2;
                int zrr = f >> 4, nn4 = f & 15;
                int c = cb + 64 * (zrr >> 4) + 16 * (to + 1) + (zrr & 15);
                nxt[k2] = *(const float4*)(x + ((size_t)b * CH + c) * NSP + n0 + nn4 * 4);
            }
        }

        #pragma unroll
        for (int k2 = 0; k2 < 4; ++k2) {
            int f = t + 256 * k2;
            int zrr = f >> 4, nn4 = f & 15;
            int c = cb + 64 * (zrr >> 4) + 16 * to + (zrr & 15);
            float4 z = *(const float4*)(z_lds + zrr * 68 + nn4 * 4);
            float iv = inv[c], ov = off[c];
            size_t idx = ((size_t)b * CH + c) * NSP + n0 + nn4 * 4;
            float4 o;
            o.x = z.x * iv + ov + xv[k2].x;
            o.y = z.y * iv + ov + xv[k2].y;
            o.z = z.z * iv + ov + xv[k2].z;
            o.w = z.w * iv + ov + xv[k2].w;
            *(float4*)(out + idx) = o;
        }

        if (to < 3) {
            #pragma unroll
            for (int k2 = 0; k2 < 4; ++k2) xv[k2] = nxt[k2];
            __syncthreads();   // z reads done before next slab's writes
        }
    }
}

// ---------------------------------------------------------------------------
extern "C" void kernel_launch(void* const* d_in, const int* in_sizes, int n_in,
                              void* d_out, int out_size, void* d_ws, size_t ws_size,
                              hipStream_t stream)
{
    const float* x     = (const float*)d_in[0];
    const float* tw    = (const float*)d_in[1];
    const float* tb    = (const float*)d_in[2];
    const float* pw    = (const float*)d_in[3];
    const float* pb    = (const float*)d_in[4];
    const float* gw    = (const float*)d_in[5];
    const float* gb_   = (const float*)d_in[6];
    const float* ww    = (const float*)d_in[7];
    const float* wb    = (const float*)d_in[8];
    const float* gamma = (const float*)d_in[9];
    const float* beta  = (const float*)d_in[10];
    const float* mean  = (const float*)d_in[11];
    const float* var   = (const float*)d_in[12];
    float* out = (float*)d_out;

    char* ws = (char*)d_ws;
    f16* xT    = (f16*)ws;                    //  67108864 B
    f16* theta = (f16*)(ws + 67108864);       //  16777216 B
    f16* phiT  = (f16*)(ws + 83886080);       //  16777216 B
    f16* gT    = (f16*)(ws + 100663296);      //  16777216 B
    f16* yv    = (f16*)(ws + 117440512);      //  16777216 B
    f16* w_all = (f16*)(ws + 134217728);      //  4*524288 B
    float* inv  = (float*)(ws + 136314880);   //  4096 B
    float* offv = (float*)(ws + 136318976);   //  4096 B

    k_prep<<<4100, 256, 0, stream>>>(tw, pw, gw, ww, wb, gamma, beta, mean, var,
                                     w_all, inv, offv);
    k_transpose_x<<<dim3(32, 16, 16), 256, 0, stream>>>(x, xT);
    k_qkv<<<dim3(32, 16, 3), 256, 0, stream>>>(xT, w_all, tb, pb, gb_, theta, phiT, gT);
    k_attn<<<dim3(16, 32), 256, 0, stream>>>(theta, phiT, gT, yv);
    k_out<<<dim3(32, 4, 16), 256, 0, stream>>>(yv, w_all + 3 * 262144, inv, offv, x, out);
}

// Round 6
// 471.221 us; speedup vs baseline: 1.0194x; 1.0194x over previous
//
#include <hip/hip_runtime.h>
#include <cstdint>

#define BATCH 16
#define CH 1024
#define CIN 256
#define NSP 2048   // H*W = 64*32
#define BN_EPS 1e-5f

typedef _Float16 f16;
typedef f16   f16x4 __attribute__((ext_vector_type(4)));
typedef f16   f16x8 __attribute__((ext_vector_type(8)));
typedef float f32x4 __attribute__((ext_vector_type(4)));
typedef float f32x16 __attribute__((ext_vector_type(16)));

typedef __attribute__((address_space(3))) void lds_t;
typedef __attribute__((address_space(1))) const void gbl_t;

// async 16B/lane global->LDS (LDS dest = wave-uniform base + lane*16)
__device__ __forceinline__ void gld16(void* l, const void* g) {
    __builtin_amdgcn_global_load_lds((gbl_t*)g, (lds_t*)l, 16, 0, 0);
}

// ---------------------------------------------------------------------------
// P0: weights -> fp16; fold BN+bias into inv/off
// ---------------------------------------------------------------------------
__global__ __launch_bounds__(256) void k_prep(
    const float* __restrict__ tw, const float* __restrict__ pw,
    const float* __restrict__ gw, const float* __restrict__ ww,
    const float* __restrict__ wb, const float* __restrict__ gamma,
    const float* __restrict__ beta, const float* __restrict__ mean,
    const float* __restrict__ var,
    f16* __restrict__ w_all, float* __restrict__ inv_out, float* __restrict__ off_out)
{
    int id = blockIdx.x * 256 + threadIdx.x;
    if (id < 4 * 262144) {
        int sel = id >> 18, off = id & 262143;
        const float* src = sel == 0 ? tw : sel == 1 ? pw : sel == 2 ? gw : ww;
        w_all[id] = (f16)src[off];
    } else {
        int c = id - 4 * 262144;
        if (c < CH) {
            float iv = gamma[c] * rsqrtf(var[c] + BN_EPS);
            inv_out[c] = iv;
            off_out[c] = (wb[c] - mean[c]) * iv + beta[c];
        }
    }
}

// ---------------------------------------------------------------------------
// P1: x [B,C,N] fp32 -> xT [B,N,C] fp16
// ---------------------------------------------------------------------------
__global__ __launch_bounds__(256) void k_transpose_x(
    const float* __restrict__ x, f16* __restrict__ xT)
{
    __shared__ float tile[64 * 65];
    int t = threadIdx.x;
    int n0 = blockIdx.x * 64, c0 = blockIdx.y * 64, b = blockIdx.z;
    const float* xb = x + (size_t)b * CH * NSP;
    for (int k = 0; k < 4; ++k) {
        int id = t + 256 * k;
        int row = id >> 4, cc = id & 15;
        float4 v = *(const float4*)(xb + (size_t)(c0 + row) * NSP + n0 + cc * 4);
        tile[row * 65 + cc * 4 + 0] = v.x;
        tile[row * 65 + cc * 4 + 1] = v.y;
        tile[row * 65 + cc * 4 + 2] = v.z;
        tile[row * 65 + cc * 4 + 3] = v.w;
    }
    __syncthreads();
    f16* xTb = xT + (size_t)b * NSP * CH;
    for (int k = 0; k < 2; ++k) {
        int id = t + 256 * k;
        int n = id >> 3, c8 = id & 7;
        f16x8 o;
        #pragma unroll
        for (int j = 0; j < 8; ++j) o[j] = (f16)tile[(c8 * 8 + j) * 65 + n];
        *(f16x8*)(xTb + (size_t)(n0 + n) * CH + c0 + c8 * 8) = o;
    }
}

// ---------------------------------------------------------------------------
// K1: QKV projections, m97-style: BK=64, global_load_lds(16B) staging into
// XOR-swizzled unpadded LDS tiles. grid (N/64, B, 3); tile 64n x 256o.
// ---------------------------------------------------------------------------
__global__ __launch_bounds__(256, 3) void k_qkv(
    const f16* __restrict__ xT, const f16* __restrict__ w_all,
    const float* __restrict__ tb, const float* __restrict__ pb,
    const float* __restrict__ gb,
    f16* __restrict__ theta, f16* __restrict__ phiT, f16* __restrict__ gT)
{
    __shared__ char smem[40960];
    f16* a_lds = (f16*)smem;            // [64][64]  swizzled (8 KB)
    f16* b_lds = (f16*)(smem + 8192);   // [256][64] swizzled (32 KB)
    int t = threadIdx.x;
    int w = t >> 6, lane = t & 63, l15 = lane & 15, q = lane >> 4;
    int sw = l15 & 7;
    int n0 = blockIdx.x * 64, b = blockIdx.y, set = blockIdx.z;
    const f16* W  = w_all + (size_t)set * (CIN * CH);
    const f16* xA = xT + ((size_t)b * NSP + n0) * CH;

    int rA  = lane >> 3;             // row-in-window 0..7
    int ccs = (lane & 7) ^ rA;       // swizzled global chunk for this lane

    f32x4 acc[4][4];
    #pragma unroll
    for (int i = 0; i < 4; ++i)
        #pragma unroll
        for (int j = 0; j < 4; ++j) acc[i][j] = (f32x4){0.f, 0.f, 0.f, 0.f};

    for (int it = 0; it < 16; ++it) {
        #pragma unroll
        for (int i = 0; i < 2; ++i) {
            int win = w * 2 + i;
            int n = win * 8 + rA;
            gld16((char*)a_lds + win * 1024,
                  xA + (size_t)n * CH + it * 64 + ccs * 8);
        }
        #pragma unroll
        for (int i = 0; i < 8; ++i) {
            int win = w * 8 + i;
            int o = win * 8 + rA;
            gld16((char*)b_lds + win * 1024,
                  W + (size_t)o * CH + it * 64 + ccs * 8);
        }
        __syncthreads();

        #pragma unroll
        for (int kl = 0; kl < 2; ++kl) {
            int c16 = kl * 4 + q;
            int pos = (c16 ^ sw) & 7;
            f16x8 af[4], bfr[4];
            #pragma unroll
            for (int tn = 0; tn < 4; ++tn)
                af[tn] = *(const f16x8*)(a_lds + (16 * tn + l15) * 64 + pos * 8);
            #pragma unroll
            for (int to = 0; to < 4; ++to)
                bfr[to] = *(const f16x8*)(b_lds + (64 * w + 16 * to + l15) * 64 + pos * 8);
            #pragma unroll
            for (int tn = 0; tn < 4; ++tn)
                #pragma unroll
                for (int to = 0; to < 4; ++to)
                    acc[tn][to] = __builtin_amdgcn_mfma_f32_16x16x32_f16(
                        af[tn], bfr[to], acc[tn][to], 0, 0, 0);
        }
        __syncthreads();
    }

    const float* bias = set == 0 ? tb : set == 1 ? pb : gb;
    float bv[4];
    #pragma unroll
    for (int to = 0; to < 4; ++to) bv[to] = bias[64 * w + 16 * to + l15];

    if (set < 2) {
        f16* e_lds = (f16*)smem;  // [64][256]
        #pragma unroll
        for (int tn = 0; tn < 4; ++tn)
            #pragma unroll
            for (int to = 0; to < 4; ++to)
                #pragma unroll
                for (int r = 0; r < 4; ++r)
                    e_lds[(16 * tn + 4 * q + r) * 256 + 64 * w + 16 * to + l15] =
                        (f16)(acc[tn][to][r] + bv[to]);
        __syncthreads();
        f16* dst = (set == 0 ? theta : phiT) + ((size_t)b * NSP + n0) * CIN;
        for (int k2 = 0; k2 < 8; ++k2) {
            int id = t + 256 * k2;
            *(f16x8*)(dst + id * 8) = *(const f16x8*)(e_lds + id * 8);
        }
    } else {
        f16* e_lds = (f16*)smem;  // [256][72]
        #pragma unroll
        for (int tn = 0; tn < 4; ++tn)
            #pragma unroll
            for (int to = 0; to < 4; ++to)
                #pragma unroll
                for (int r = 0; r < 4; ++r)
                    e_lds[(64 * w + 16 * to + l15) * 72 + 16 * tn + 4 * q + r] =
                        (f16)(acc[tn][to][r] + bv[to]);
        __syncthreads();
        f16* dst = gT + (size_t)b * CIN * NSP + n0;
        for (int k2 = 0; k2 < 8; ++k2) {
            int id = t + 256 * k2;
            int o = id >> 3, cc = id & 7;
            *(f16x8*)(dst + (size_t)o * NSP + cc * 8) = *(const f16x8*)(e_lds + o * 72 + cc * 8);
        }
    }
}

// ---------------------------------------------------------------------------
// K2: flash attention v6 -- v5's 32x32 wave decomposition, but with RAW
// s_barrier + manually-counted s_waitcnt (T3/T4): no vmcnt(0) drains inside
// the loop, so staging loads span barriers.
//   g: reg-staged (8 x b128 issued at iter top, sched_barrier-pinned,
//      ds_written after PV under vmcnt(8)).
//   phi: gld16 DMA issued after barrier A, waited at iter entry vmcnt(0).
// S split into 2 independent MFMA chains; setprio around MFMA clusters.
// grid (B, N/64) for XCD pinning. LDS 76KB -> 2 blocks/CU.
// ---------------------------------------------------------------------------
__global__ __launch_bounds__(256, 2) void k_attn(
    const f16* __restrict__ theta, const f16* __restrict__ phiT,
    const f16* __restrict__ gT, f16* __restrict__ y)
{
    __shared__ char smem[76032];
    f16* phi_lds = (f16*)smem;                 // [64][256] swizzled (32 KB)
    f16* g_lds   = (f16*)(smem + 32768);       // [256][64] swizzled (32 KB)
    f16* p_lds   = (f16*)(smem + 65536);       // [64][72]  (9216 B)
    float* pmax_lds  = (float*)(smem + 74752); // [2][64]
    float* psum_lds  = (float*)(smem + 75264); // [2][64]
    float* alpha_lds = (float*)(smem + 75776); // [64]

    int t = threadIdx.x;
    int w = t >> 6, lane = t & 63;
    int l31 = lane & 31, hi = lane >> 5;
    int qh = w & 1, kh = w >> 1;
    int b = blockIdx.x, n0 = blockIdx.y * 64;

    const f16* thb  = theta + (size_t)b * NSP * CIN;
    const f16* phib = phiT + (size_t)b * NSP * CIN;
    const f16* gTb  = gT + (size_t)b * CIN * NSP;

    // theta regs (B-operand): col q = n0+32qh+l31, k = 16*step + 8*hi + j
    f16x8 th[16];
    {
        const f16* tp = thb + (size_t)(n0 + qh * 32 + l31) * CIN + 8 * hi;
        #pragma unroll
        for (int s = 0; s < 16; ++s) th[s] = *(const f16x8*)(tp + s * 16);
    }

    f32x16 acc[2][2];   // [Mt: q-half][Nt: cin sub-tile of this wave's quarter]
    #pragma unroll
    for (int i = 0; i < 2; ++i)
        #pragma unroll
        for (int j = 0; j < 2; ++j)
            #pragma unroll
            for (int r = 0; r < 16; ++r) acc[i][j][r] = 0.f;
    float m_run = -INFINITY, l_run = 0.f;

    // phi DMA: 32 windows of 1KB = 2 rows x 512B. lane -> (row_in=hi, chunk)
    int p_cdst = lane & 31;
    // g DMA (prologue only): 32 windows of 1KB = 8 rows x 128B
    int g_rin = lane >> 3, g_cdst = lane & 7;
    // g reg staging: thread t covers chunk gc8 of rows grb+32j
    int gc8 = t & 7, grb = t >> 3;

    #define DMA_PHI(IT)                                                         \
        _Pragma("unroll")                                                       \
        for (int i_ = 0; i_ < 8; ++i_) {                                        \
            int win_ = w * 8 + i_;                                              \
            int row_ = win_ * 2 + hi;                                           \
            int cs_ = (p_cdst & 24) | ((p_cdst ^ row_) & 7);                    \
            gld16((char*)phi_lds + win_ * 1024,                                 \
                  phib + (size_t)((IT) * 64 + row_) * CIN + cs_ * 8);           \
        }
    #define DMA_G0()                                                            \
        _Pragma("unroll")                                                       \
        for (int i_ = 0; i_ < 8; ++i_) {                                        \
            int win_ = w * 8 + i_;                                              \
            int row_ = win_ * 8 + g_rin;                                        \
            int cs_ = g_cdst ^ (row_ & 7);                                      \
            gld16((char*)g_lds + win_ * 1024,                                   \
                  gTb + (size_t)row_ * NSP + cs_ * 8);                          \
        }

    // prologue: tile 0 fully via DMA; wait + barrier
    DMA_PHI(0)
    DMA_G0()
    asm volatile("s_waitcnt vmcnt(0)" ::: "memory");
    __builtin_amdgcn_s_barrier();

    int srow = kh * 32 + l31;        // phi row for S A-operand
    int qrow = qh * 32 + l31;        // this thread's softmax q-column
    int mli  = kh * 64 + qrow;       // partial-max/sum slot

    f16x8 gr[8];

    for (int it = 0; it < 32; ++it) {
        // issue next g tile -> regs (covered by S + softmax + PV)
        if (it < 31) {
            #pragma unroll
            for (int j = 0; j < 8; ++j)
                gr[j] = *(const f16x8*)(gTb + (size_t)(grb + 32 * j) * NSP
                                        + (it + 1) * 64 + gc8 * 8);
        }
        __builtin_amdgcn_sched_barrier(0);

        // ---- S^T subtile: D[m=k(32,kh)][n=q(32,qh)], K=256, 2 indep chains
        f32x16 s0, s1;
        #pragma unroll
        for (int r = 0; r < 16; ++r) { s0[r] = 0.f; s1[r] = 0.f; }
        __builtin_amdgcn_s_setprio(1);
        #pragma unroll
        for (int s = 0; s < 8; ++s) {
            int ch0 = 2 * s + hi;
            int sl0 = (ch0 & 24) | ((ch0 ^ srow) & 7);
            f16x8 a0 = *(const f16x8*)(phi_lds + srow * 256 + sl0 * 8);
            s0 = __builtin_amdgcn_mfma_f32_32x32x16_f16(a0, th[s], s0, 0, 0, 0);
            int ch1 = 2 * (s + 8) + hi;
            int sl1 = (ch1 & 24) | ((ch1 ^ srow) & 7);
            f16x8 a1 = *(const f16x8*)(phi_lds + srow * 256 + sl1 * 8);
            s1 = __builtin_amdgcn_mfma_f32_32x32x16_f16(a1, th[s + 8], s1, 0, 0, 0);
        }
        __builtin_amdgcn_s_setprio(0);
        f32x16 sacc = s0 + s1;

        // ---- partial max over this wave's 32 k-rows for col qrow
        float tmax = sacc[0];
        #pragma unroll
        for (int r = 1; r < 16; ++r) tmax = fmaxf(tmax, sacc[r]);
        tmax = fmaxf(tmax, __shfl_xor(tmax, 32));
        if (lane < 32) pmax_lds[mli] = tmax;
        asm volatile("s_waitcnt lgkmcnt(0)" ::: "memory");
        __builtin_amdgcn_s_barrier();                      // A: pmax visible

        // phi DMA for next tile (phi reads all done at A; waited at entry)
        if (it < 31) DMA_PHI(it + 1)

        float tile_max = fmaxf(tmax, pmax_lds[mli ^ 64]);
        float mnew  = fmaxf(m_run, tile_max);
        float alpha = __expf(m_run - mnew);
        m_run = mnew;
        float rs = 0.f;
        float pv[16];
        #pragma unroll
        for (int r = 0; r < 16; ++r) {
            pv[r] = __expf(sacc[r] - mnew);
            rs += pv[r];
        }
        rs += __shfl_xor(rs, 32);
        if (lane < 32) {
            psum_lds[mli] = rs;
            if (kh == 0) alpha_lds[qrow] = alpha;
        }
        // P -> p_lds [q][72]: k = kh*32 + 8*g4 + 4*hi + rr
        #pragma unroll
        for (int g4 = 0; g4 < 4; ++g4) {
            f16x4 pk = { (f16)pv[4*g4+0], (f16)pv[4*g4+1], (f16)pv[4*g4+2], (f16)pv[4*g4+3] };
            *(f16x4*)(p_lds + qrow * 72 + kh * 32 + 8 * g4 + 4 * hi) = pk;
        }
        asm volatile("s_waitcnt lgkmcnt(0)" ::: "memory");
        __builtin_amdgcn_s_barrier();                      // B: P/psum/alpha

        l_run = l_run * alpha + rs + psum_lds[mli ^ 64];

        // ---- rescale yacc (rows are reg-indexed q; alpha via LDS broadcast)
        f32x4 av[2][4];
        float mn = 1.0f;
        #pragma unroll
        for (int Mt = 0; Mt < 2; ++Mt)
            #pragma unroll
            for (int g4 = 0; g4 < 4; ++g4) {
                av[Mt][g4] = *(const f32x4*)(alpha_lds + Mt * 32 + 8 * g4 + 4 * hi);
                mn = fminf(mn, fminf(fminf(av[Mt][g4][0], av[Mt][g4][1]),
                                     fminf(av[Mt][g4][2], av[Mt][g4][3])));
            }
        if (__any(mn < 1.0f)) {
            #pragma unroll
            for (int Mt = 0; Mt < 2; ++Mt)
                #pragma unroll
                for (int g4 = 0; g4 < 4; ++g4)
                    #pragma unroll
                    for (int rr = 0; rr < 4; ++rr) {
                        acc[Mt][0][4*g4+rr] *= av[Mt][g4][rr];
                        acc[Mt][1][4*g4+rr] *= av[Mt][g4][rr];
                    }
        }

        // ---- PV: D[m=q][n=cin(wave quarter)], K=64 in 4 steps
        __builtin_amdgcn_s_setprio(1);
        #pragma unroll
        for (int ks = 0; ks < 4; ++ks) {
            f16x8 pa0 = *(const f16x8*)(p_lds + l31 * 72 + ks * 16 + 8 * hi);
            f16x8 pa1 = *(const f16x8*)(p_lds + (32 + l31) * 72 + ks * 16 + 8 * hi);
            int slot = (2 * ks + hi) ^ (l31 & 7);
            f16x8 gb0 = *(const f16x8*)(g_lds + (64 * w + l31) * 64 + slot * 8);
            f16x8 gb1 = *(const f16x8*)(g_lds + (64 * w + 32 + l31) * 64 + slot * 8);
            acc[0][0] = __builtin_amdgcn_mfma_f32_32x32x16_f16(pa0, gb0, acc[0][0], 0, 0, 0);
            acc[0][1] = __builtin_amdgcn_mfma_f32_32x32x16_f16(pa0, gb1, acc[0][1], 0, 0, 0);
            acc[1][0] = __builtin_amdgcn_mfma_f32_32x32x16_f16(pa1, gb0, acc[1][0], 0, 0, 0);
            acc[1][1] = __builtin_amdgcn_mfma_f32_32x32x16_f16(pa1, gb1, acc[1][1], 0, 0, 0);
        }
        __builtin_amdgcn_s_setprio(0);
        asm volatile("s_waitcnt lgkmcnt(0)" ::: "memory");
        __builtin_amdgcn_s_barrier();                      // C: PV reads done

        if (it < 31) {
            // g-loads are the 8 oldest VMEM ops (phi DMA's 8 follow them)
            asm volatile("s_waitcnt vmcnt(8)" ::: "memory");
            #pragma unroll
            for (int j = 0; j < 8; ++j) {
                int o = grb + 32 * j;
                *(f16x8*)(g_lds + o * 64 + (gc8 ^ (o & 7)) * 8) = gr[j];
            }
            // entry for it+1: phi DMA landed + g writes visible
            asm volatile("s_waitcnt vmcnt(0) lgkmcnt(0)" ::: "memory");
            __builtin_amdgcn_s_barrier();                  // ENTRY(it+1)
        }
    }

    // ---- epilogue: y = acc / l, via LDS bounce for coalesced stores
    if (lane < 32 && kh == 0) alpha_lds[qrow] = 1.0f / l_run;
    __syncthreads();
    f16* e_lds = (f16*)smem;   // [64][264]
    #pragma unroll
    for (int Mt = 0; Mt < 2; ++Mt)
        #pragma unroll
        for (int g4 = 0; g4 < 4; ++g4) {
            f32x4 lv = *(const f32x4*)(alpha_lds + Mt * 32 + 8 * g4 + 4 * hi);
            #pragma unroll
            for (int rr = 0; rr < 4; ++rr) {
                int q = Mt * 32 + 8 * g4 + 4 * hi + rr;
                #pragma unroll
                for (int Nt = 0; Nt < 2; ++Nt) {
                    int cin = 64 * w + Nt * 32 + l31;
                    e_lds[q * 264 + cin] = (f16)(acc[Mt][Nt][4*g4+rr] * lv[rr]);
                }
            }
        }
    __syncthreads();
    f16* dst = y + ((size_t)b * NSP + n0) * CIN;
    for (int k2 = 0; k2 < 8; ++k2) {
        int id = t + 256 * k2;
        int row = id >> 5, cc = id & 31;
        *(f16x8*)(dst + (size_t)row * CIN + cc * 8) = *(const f16x8*)(e_lds + row * 264 + cc * 8);
    }
    #undef DMA_PHI
    #undef DMA_G0
}

// ---------------------------------------------------------------------------
// K3: Z = w_w . y^T + BN + residual, k_qkv m97 structure.
// Tile 64n x 256c, K=CIN=256 in 4 BK=64 steps, gld16 -> swizzled LDS for
// BOTH operands. grid (N/64, C/256, B) = (32,4,16).
// ---------------------------------------------------------------------------
__global__ __launch_bounds__(256, 3) void k_out(
    const f16* __restrict__ yv, const f16* __restrict__ ww,
    const float* __restrict__ inv, const float* __restrict__ off,
    const float* __restrict__ x, float* __restrict__ out)
{
    __shared__ char smem[40960];
    f16*   a_lds = (f16*)smem;            // [64][64]  y tile, swizzled (8 KB)
    f16*   b_lds = (f16*)(smem + 8192);   // [256][64] w tile, swizzled (32 KB)
    float* z_lds = (float*)smem;          // [64][68] f32 bounce (17.4 KB, alias)
    int t = threadIdx.x;
    int w = t >> 6, lane = t & 63, l15 = lane & 15, q = lane >> 4;
    int sw = l15 & 7;
    int n0 = blockIdx.x * 64, cb = blockIdx.y * 256, b = blockIdx.z;

    const f16* yA = yv + ((size_t)b * NSP + n0) * CIN;
    const f16* W  = ww + (size_t)cb * CIN;

    int rA  = lane >> 3;             // row-in-window 0..7
    int ccs = (lane & 7) ^ rA;       // swizzled global chunk for this lane

    f32x4 acc[4][4];
    #pragma unroll
    for (int i = 0; i < 4; ++i)
        #pragma unroll
        for (int j = 0; j < 4; ++j) acc[i][j] = (f32x4){0.f, 0.f, 0.f, 0.f};

    for (int it = 0; it < 4; ++it) {
        #pragma unroll
        for (int i = 0; i < 2; ++i) {
            int win = w * 2 + i;
            int n = win * 8 + rA;
            gld16((char*)a_lds + win * 1024,
                  yA + (size_t)n * CIN + it * 64 + ccs * 8);
        }
        #pragma unroll
        for (int i = 0; i < 8; ++i) {
            int win = w * 8 + i;
            int o = win * 8 + rA;
            gld16((char*)b_lds + win * 1024,
                  W + (size_t)o * CIN + it * 64 + ccs * 8);
        }
        __syncthreads();

        #pragma unroll
        for (int kl = 0; kl < 2; ++kl) {
            int c16 = kl * 4 + q;
            int pos = (c16 ^ sw) & 7;
            f16x8 af[4], bfr[4];
            #pragma unroll
            for (int tn = 0; tn < 4; ++tn)
                af[tn] = *(const f16x8*)(a_lds + (16 * tn + l15) * 64 + pos * 8);
            #pragma unroll
            for (int to = 0; to < 4; ++to)
                bfr[to] = *(const f16x8*)(b_lds + (64 * w + 16 * to + l15) * 64 + pos * 8);
            #pragma unroll
            for (int tn = 0; tn < 4; ++tn)
                #pragma unroll
                for (int to = 0; to < 4; ++to)
                    acc[tn][to] = __builtin_amdgcn_mfma_f32_16x16x32_f16(
                        af[tn], bfr[to], acc[tn][to], 0, 0, 0);
        }
        __syncthreads();
    }

    // ---- epilogue: 4 slabs over `to` (c-fragment); z bounce for coalescing.
    float4 xv[4];
    #pragma unroll
    for (int k2 = 0; k2 < 4; ++k2) {
        int f = t + 256 * k2;
        int zrr = f >> 4, nn4 = f & 15;
        int c = cb + 64 * (zrr >> 4) + (zrr & 15);   // to = 0
        xv[k2] = *(const float4*)(x + ((size_t)b * CH + c) * NSP + n0 + nn4 * 4);
    }

    #pragma unroll
    for (int to = 0; to < 4; ++to) {
        #pragma unroll
        for (int tn = 0; tn < 4; ++tn)
            #pragma unroll
            for (int r = 0; r < 4; ++r)
                z_lds[(16 * w + l15) * 68 + 16 * tn + 4 * q + r] = acc[tn][to][r];
        __syncthreads();

        float4 nxt[4];
        if (to < 3) {
            #pragma unroll
            for (int k2 = 0; k2 < 4; ++k2) {
                int f = t + 256 * k2;
                int zrr = f >> 4, nn4 = f & 15;
                int c = cb + 64 * (zrr >> 4) + 16 * (to + 1) + (zrr & 15);
                nxt[k2] = *(const float4*)(x + ((size_t)b * CH + c) * NSP + n0 + nn4 * 4);
            }
        }

        #pragma unroll
        for (int k2 = 0; k2 < 4; ++k2) {
            int f = t + 256 * k2;
            int zrr = f >> 4, nn4 = f & 15;
            int c = cb + 64 * (zrr >> 4) + 16 * to + (zrr & 15);
            float4 z = *(const float4*)(z_lds + zrr * 68 + nn4 * 4);
            float iv = inv[c], ov = off[c];
            size_t idx = ((size_t)b * CH + c) * NSP + n0 + nn4 * 4;
            float4 o;
            o.x = z.x * iv + ov + xv[k2].x;
            o.y = z.y * iv + ov + xv[k2].y;
            o.z = z.z * iv + ov + xv[k2].z;
            o.w = z.w * iv + ov + xv[k2].w;
            *(float4*)(out + idx) = o;
        }

        if (to < 3) {
            #pragma unroll
            for (int k2 = 0; k2 < 4; ++k2) xv[k2] = nxt[k2];
            __syncthreads();   // z reads done before next slab's writes
        }
    }
}

// ---------------------------------------------------------------------------
extern "C" void kernel_launch(void* const* d_in, const int* in_sizes, int n_in,
                              void* d_out, int out_size, void* d_ws, size_t ws_size,
                              hipStream_t stream)
{
    const float* x     = (const float*)d_in[0];
    const float* tw    = (const float*)d_in[1];
    const float* tb    = (const float*)d_in[2];
    const float* pw    = (const float*)d_in[3];
    const float* pb    = (const float*)d_in[4];
    const float* gw    = (const float*)d_in[5];
    const float* gb_   = (const float*)d_in[6];
    const float* ww    = (const float*)d_in[7];
    const float* wb    = (const float*)d_in[8];
    const float* gamma = (const float*)d_in[9];
    const float* beta  = (const float*)d_in[10];
    const float* mean  = (const float*)d_in[11];
    const float* var   = (const float*)d_in[12];
    float* out = (float*)d_out;

    char* ws = (char*)d_ws;
    f16* xT    = (f16*)ws;                    //  67108864 B
    f16* theta = (f16*)(ws + 67108864);       //  16777216 B
    f16* phiT  = (f16*)(ws + 83886080);       //  16777216 B
    f16* gT    = (f16*)(ws + 100663296);      //  16777216 B
    f16* yv    = (f16*)(ws + 117440512);      //  16777216 B
    f16* w_all = (f16*)(ws + 134217728);      //  4*524288 B
    float* inv  = (float*)(ws + 136314880);   //  4096 B
    float* offv = (float*)(ws + 136318976);   //  4096 B

    k_prep<<<4100, 256, 0, stream>>>(tw, pw, gw, ww, wb, gamma, beta, mean, var,
                                     w_all, inv, offv);
    k_transpose_x<<<dim3(32, 16, 16), 256, 0, stream>>>(x, xT);
    k_qkv<<<dim3(32, 16, 3), 256, 0, stream>>>(xT, w_all, tb, pb, gb_, theta, phiT, gT);
    k_attn<<<dim3(16, 32), 256, 0, stream>>>(theta, phiT, gT, yv);
    k_out<<<dim3(32, 4, 16), 256, 0, stream>>>(yv, w_all + 3 * 262144, inv, offv, x, out);
}